// Round 3
// 81.262 us; speedup vs baseline: 1.0023x; 1.0023x over previous
//
#include <hip/hip_runtime.h>
#include <math.h>

// AFM: B=4096, F=50, D=16, A=32, P=1225 pairs.
// out[b] = sum_p softmax_p( relu(inter_p @ W) . h ) * (inter_p . p_vec)
//
// Round 18 (resubmit; R2 was a broker timeout, kernel never ran):
// R17's MFMA-offload of both dot-reductions, with the broken
// permlane32_swap DELETED. Key insight: the score MFMA's A-operand is a
// broadcast constant, so the C-layout row permutation is absorbed into the
// h-coefficients instead of reshuffling data across lane-halves:
//   lane (col n, half h) holds z rows a = 4h + (jj&3) + 8*(jj>>2) in reg jj;
//   its B-slot is k = 8h + jj; set A2[jj] = h[a(jj,h)]*log2e. Sum over k
//   covers all 32 a regardless of per-lane order. Zero cross-lane ops in
//   the main loop.
//  - g = inter.pvec: 1 MFMA, broadcast-pvec A, same B fragment; g[0] full.
//  - Score: cvt_pkrtz + pk_max packs ARE the B-fragments (BL=q0..3, BH=q4..7);
//    2 MFMAs accumulate both a-halves; s[0] = full score. Old phase-C fdot2
//    chain (8/tile), g fdot2 (4/tile) and phase-D shfl (1/tile) all deleted.
//  - Layouts (validated R4-R16 + m74/m101): A[m=lane&31][k=(lane>>5)*8+jj],
//    B[k][n=lane&31], C/D row=(reg&3)+8*(reg>>2)+4*(lane>>5), col=lane&31.
//  - Staging, table, grid 512x512, BPB=8 unchanged from R12/R16.

#define FF 50
#define DD 16
#define AA 32
#define NP 1225
#define NT 39
#define NQ4 10             // quad-groups of tiles (40 slots)
#define ERS 24             // halves per e-row (48 B)
#define EBS (FF * ERS)     // 1200 halves per batch element
#define BPB 8              // batches per block = waves per block
#define NTHR 512

typedef _Float16 half8 __attribute__((ext_vector_type(8)));
typedef _Float16 half4 __attribute__((ext_vector_type(4)));
typedef __fp16   fh2    __attribute__((ext_vector_type(2)));
typedef float    floatx16 __attribute__((ext_vector_type(16)));
typedef unsigned int uintv4 __attribute__((ext_vector_type(4)));

__global__ __launch_bounds__(NTHR, 4) void afm_kernel(
    const float* __restrict__ feat,   // [B, 50, 16]
    const float* __restrict__ W,      // [16, 32]
    const float* __restrict__ h,      // [32]
    const float* __restrict__ pvec,   // [16]
    float* __restrict__ out,          // [B]
    int Btot)
{
  __shared__ __align__(16) _Float16 eh[BPB * EBS];      // 19200 B
  __shared__ __align__(16) unsigned int tbl[NQ4 * 128]; // 5120 B, quad layout

  const int tid    = threadIdx.x;
  const int lane   = tid & 63;
  const int wave   = tid >> 6;       // 0..7, owns batch b0+wave
  const int halfid = lane >> 5;
  const int n      = lane & 31;
  const int b0     = blockIdx.x * BPB;

  // ---- stage 8 batch elements -> f16 LDS ----
  for (int s = tid; s < BPB * 200; s += NTHR) {
    int bl  = s / 200;
    int rem = s - bl * 200;
    int bb  = b0 + bl;
    if (bb < Btot) {
      float4 v4 = ((const float4*)feat)[(size_t)bb * 200 + rem];
      half4 hv;
      hv[0] = (_Float16)v4.x; hv[1] = (_Float16)v4.y;
      hv[2] = (_Float16)v4.z; hv[3] = (_Float16)v4.w;
      int row = rem >> 2, q = rem & 3;
      *(half4*)(&eh[bl * EBS + row * ERS + q * 4]) = hv;
    }
  }

  // ---- pair table, quad layout: tbl[q4*128 + n*4 + u] = ent(t=4*q4+u, n)
  //      ent = (i*48)<<16 | (j*48); 0 for pad slots ----
  for (int q = tid; q < NQ4 * 128; q += NTHR) {
    int q4  = q >> 7;
    int rem = q & 127;
    int nn  = rem >> 2;
    int u   = rem & 3;
    int p   = (4 * q4 + u) * 32 + nn;
    unsigned ent = 0;
    if (p < NP) {
      int rad = 9801 - 8 * p;
      int i = (int)((99.0f - sqrtf((float)rad)) * 0.5f);
      if (i < 0) i = 0; if (i > 48) i = 48;
      int off = (i * (99 - i)) >> 1;
      if (off > p) { --i; off = (i * (99 - i)) >> 1; }
      else {
        int off1 = ((i + 1) * (98 - i)) >> 1;
        if (off1 <= p) { ++i; off = off1; }
      }
      int j = p - off + i + 1;
      ent = ((unsigned)(i * 48) << 16) | (unsigned)(j * 48);
    }
    tbl[q] = ent;
  }

  // ---- loop-invariant fragments ----
  const float LOG2E = 1.4426950408889634f;
  half8 A0;                                   // z-MFMA: A[m=a][k=d] = W[d][a]
  #pragma unroll
  for (int jj = 0; jj < 8; ++jj)
    A0[jj] = (_Float16)W[(halfid * 8 + jj) * AA + n];
  // Score/g broadcast A-operands. Score MFMA consumes z packs in C-layout
  // row order, so permute h to match: slot k=8h+jj carries row
  // a = 4h + (jj&3) + 8*(jj>>2)  (low MFMA), +16 (high MFMA).
  half8 A2_0, A2_16, Apv;
  #pragma unroll
  for (int jj = 0; jj < 8; ++jj) {
    int arow = 4 * halfid + (jj & 3) + 8 * (jj >> 2);
    A2_0[jj]  = (_Float16)(h[arow]      * LOG2E);
    A2_16[jj] = (_Float16)(h[16 + arow] * LOG2E);
    Apv[jj]   = (_Float16)pvec[halfid * 8 + jj];   // standard k=d order
  }
  const floatx16 ZACC = (floatx16)0.0f;
  const fh2 zz = {(__fp16)0.f, (__fp16)0.f};

  __syncthreads();

  // ---- main loop: this wave owns batch b0+wave ----
  const char* eb = (const char*)(eh + wave * EBS) + halfid * 16;
  const unsigned int* tq = tbl + n * 4;       // this lane's quad column

#if __has_builtin(__builtin_amdgcn_exp2f)
  #define EXP2(x) __builtin_amdgcn_exp2f(x)
#else
  #define EXP2(x) exp2f(x)
#endif

  auto mkB = [&](unsigned ij) -> half8 {
    half8 Bi = *(const half8*)(eb + (ij >> 16));
    half8 Bj = *(const half8*)(eb + (ij & 0xffffu));
    return Bi * Bj;                           // 4x v_pk_mul_f16
  };

  // cvt+relu the 16 z regs into two B-fragments (no cross-lane motion;
  // the per-lane row order is compensated in A2_0/A2_16).
  auto score_frags = [&](const floatx16& z, half8& BL, half8& BH) {
    unsigned q[8];
    #pragma unroll
    for (int i = 0; i < 8; ++i) {
      fh2 zp = __builtin_amdgcn_cvt_pkrtz(z[2 * i], z[2 * i + 1]);
      fh2 zr = __builtin_elementwise_max(zp, zz);     // v_pk_max_f16
      q[i] = __builtin_bit_cast(unsigned, zr);
    }
    uintv4 bl = {q[0], q[1], q[2], q[3]};
    uintv4 bh = {q[4], q[5], q[6], q[7]};
    BL = __builtin_bit_cast(half8, bl);
    BH = __builtin_bit_cast(half8, bh);
  };

  float den0 = 0.f, num0 = 0.f, den1 = 0.f, num1 = 0.f;

  auto tilepair = [&](unsigned ija, unsigned ijb) {
    half8 Ba = mkB(ija);
    half8 Bb = mkB(ijb);
    // g and z: 4 independent MFMAs on the same B fragments
    floatx16 gA = __builtin_amdgcn_mfma_f32_32x32x16_f16(Apv, Ba, ZACC, 0, 0, 0);
    floatx16 gB = __builtin_amdgcn_mfma_f32_32x32x16_f16(Apv, Bb, ZACC, 0, 0, 0);
    floatx16 za = __builtin_amdgcn_mfma_f32_32x32x16_f16(A0, Ba, ZACC, 0, 0, 0);
    floatx16 zb = __builtin_amdgcn_mfma_f32_32x32x16_f16(A0, Bb, ZACC, 0, 0, 0);
    float ga = gA[0], gb = gB[0];             // full g (K-reduced over d)
    half8 BLa, BHa, BLb, BHb;
    score_frags(za, BLa, BHa);
    score_frags(zb, BLb, BHb);
    floatx16 sa = __builtin_amdgcn_mfma_f32_32x32x16_f16(A2_0, BLa, ZACC, 0, 0, 0);
    sa = __builtin_amdgcn_mfma_f32_32x32x16_f16(A2_16, BHa, sa, 0, 0, 0);
    floatx16 sb = __builtin_amdgcn_mfma_f32_32x32x16_f16(A2_0, BLb, ZACC, 0, 0, 0);
    sb = __builtin_amdgcn_mfma_f32_32x32x16_f16(A2_16, BHb, sb, 0, 0, 0);
    float exa = EXP2(sa[0]);                  // full score, both a-halves
    float exb = EXP2(sb[0]);
    den0 += exa; num0 = fmaf(exa, ga, num0);
    den1 += exb; num1 = fmaf(exb, gb, num1);
  };

  for (int q4 = 0; q4 < 9; ++q4) {            // tiles 0..35, all valid
    uint4 cur = *(const uint4*)(tq + (q4 << 7));
    tilepair(cur.x, cur.y);
    tilepair(cur.z, cur.w);
  }
  {                                           // quad 9: tiles 36,37 + 38(partial)
    uint4 cur = *(const uint4*)(tq + (9 << 7));
    tilepair(cur.x, cur.y);
    half8 Bc = mkB(cur.z);
    floatx16 gC = __builtin_amdgcn_mfma_f32_32x32x16_f16(Apv, Bc, ZACC, 0, 0, 0);
    floatx16 zc = __builtin_amdgcn_mfma_f32_32x32x16_f16(A0, Bc, ZACC, 0, 0, 0);
    half8 BL, BH;
    score_frags(zc, BL, BH);
    floatx16 sc16 = __builtin_amdgcn_mfma_f32_32x32x16_f16(A2_0, BL, ZACC, 0, 0, 0);
    sc16 = __builtin_amdgcn_mfma_f32_32x32x16_f16(A2_16, BH, sc16, 0, 0, 0);
    float scv = (n < 9) ? sc16[0] : -3.0e38f; // tile 38: valid n < 9
    float exc = EXP2(scv);
    den0 += exc; num0 = fmaf(exc, gC[0], num0);
  }
  float den = den0 + den1, num = num0 + num1;

  // ---- butterfly: pure adds. Every (tile,n) is counted once per lane-half
  //      in BOTH num and den (score and g are full per lane) -> plain ratio.
  #pragma unroll
  for (int mask = 32; mask >= 1; mask >>= 1) {
    den += __shfl_xor(den, mask, 64);
    num += __shfl_xor(num, mask, 64);
  }
  const int b = b0 + wave;
  if (lane == 0 && b < Btot) out[b] = num / den;
}

extern "C" void kernel_launch(void* const* d_in, const int* in_sizes, int n_in,
                              void* d_out, int out_size, void* d_ws, size_t ws_size,
                              hipStream_t stream) {
  const float* feat = (const float*)d_in[0];
  const float* W    = (const float*)d_in[1];
  const float* h    = (const float*)d_in[2];
  const float* pvec = (const float*)d_in[3];
  float* out = (float*)d_out;
  const int B = in_sizes[0] / (FF * DD);   // 4096
  afm_kernel<<<(B + BPB - 1) / BPB, NTHR, 0, stream>>>(feat, W, h, pvec, out, B);
}